// Round 1
// baseline (174.217 us; speedup 1.0000x reference)
//
#include <hip/hip_runtime.h>
#include <hip/hip_fp16.h>
#include <math.h>

// MatchAttention fused forward — v2 (depth-2 prefetch + VALU diet).
// B=2, H=W=64 (N=4096), C=256, h=8 (Ch=32), 7x7=49 window.
//
// Ledger (carried forward): load batches survive ONLY when they cross a
// runtime-loop backedge (R8: VGPR 88 kept batches; R9/R10 full unroll
// collapsed them). This round: period-3 buffer rotation (A/B/C) in the
// unroll-disabled loop -> >=14 gathers in flight per compute block
// (latency theory: one-row prefetch left ~200-400cy L2 latency exposed).
// VALU diet: v_dot2_f32_f16 for the L1 reduce, exp2-prescale (k,q
// pre-multiplied by log2e -> v_exp_f32 direct, softmax invariant),
// fp16-source FMA for the V accumulate, saddr-form gathers (uniform
// 64-bit base in SGPR + 32-bit per-lane voffset).
constexpr int B = 2, H = 64, W = 64, C = 256, NH = 8, CH = 32;
constexpr int R = 3, KW = 7, KK = 49, N = H * W;
constexpr int PIX = 32;  // pixel-heads per 256-thread block (8 lanes each)
constexpr float LOG2E = 1.4426950408889634f;

typedef _Float16 h16x2 __attribute__((ext_vector_type(2)));

template <int CTRL>
static __device__ __forceinline__ float dpp_mov(float v) {
  union { float f; int i; } u;
  u.f = v;
  u.i = __builtin_amdgcn_update_dpp(u.i, u.i, CTRL, 0xf, 0xf, true);
  return u.f;
}
#define DPP_QUAD_XOR1 0xB1     // quad_perm [1,0,3,2]
#define DPP_QUAD_XOR2 0x4E     // quad_perm [2,3,0,1]
#define DPP_HALF_MIRROR 0x141  // lane i -> 7-i within each 8-lane group

static __device__ __forceinline__ h16x2 h2n(__half2 x) {
  union { __half2 h; h16x2 n; } u;
  u.h = x;
  return u.n;
}

// pack k,v fp32 -> fp16 interleaved: [b][n][g][(k0..3 v0..3) x 8] = 128B.
// k is pre-scaled by log2(e): exp2(-log2e*sum|q-k|) == exp(-sum|q-k|),
// so the match kernel feeds the raw L1 sum straight into v_exp_f32.
// v stays unscaled.
__global__ void __launch_bounds__(256) pack_kv_kernel(
    const float* __restrict__ kp, const float* __restrict__ vp,
    __half* __restrict__ kv) {
  const int idx = blockIdx.x * 256 + threadIdx.x;  // 0..524287
  const int e8 = idx & 7;
  const int g = (idx >> 3) & 7;
  const int bn = idx >> 6;  // 0..8191 = b*N+n
  const float4 kf = *(const float4*)(kp + (size_t)bn * C + g * CH + e8 * 4);
  const float4 vf = *(const float4*)(vp + (size_t)bn * C + g * CH + e8 * 4);
  __half2 o[4];
  o[0] = __floats2half2_rn(kf.x * LOG2E, kf.y * LOG2E);
  o[1] = __floats2half2_rn(kf.z * LOG2E, kf.w * LOG2E);
  o[2] = __floats2half2_rn(vf.x, vf.y);
  o[3] = __floats2half2_rn(vf.z, vf.w);
  *(float4*)(kv + ((size_t)(bn * NH + g) * 64 + e8 * 8)) = *(float4*)o;
}

union KV { float4 f; __half2 h[4]; h16x2 n[4]; };

__global__ void __launch_bounds__(256, 4) match_attn_kernel(
    const float* __restrict__ moff, const float* __restrict__ qp,
    const __half* __restrict__ kvp, float* __restrict__ outp,
    float* __restrict__ attnp) {
  const int t = threadIdx.x;
  const int e8 = t & 7;  // which 4-channel slice of the head
  const int p = t >> 3;  // pixel within block, 0..31

  // XCD swizzle: blk&7 ~ XCD; XCD x owns (b,g) pairs {2x,2x+1}
  const int xcd = blockIdx.x & 7;
  const int rest = blockIdx.x >> 3;      // 0..255
  const int bg = xcd * 2 + (rest >> 7);  // 0..15
  const int slot = rest & 127;
  const int y = slot >> 1;
  const int x = (slot & 1) * PIX + p;
  const int g = bg & 7;
  const int b = bg >> 3;
  const int n = y * W + x;

  // per-pixel, per-head rounded (dy,dx); rintf == jnp.round (half-to-even)
  const float2 off = *(const float2*)(moff + ((size_t)(b * N + n) * NH + g) * 2);
  const int cy = y + (int)rintf(off.x);
  const int cx = x + (int)rintf(off.y);

  // clamped x offsets in BYTES (pixel stride 1024B)
  int pxo[KW];
#pragma unroll
  for (int i = 0; i < KW; ++i) pxo[i] = min(max(cx + i - R, 0), W - 1) << 10;
  // wave-uniform image base (b,g are blockIdx-derived -> SGPR pair);
  // every per-lane term lives in the 32-bit voffset -> saddr-form loads.
  const char* __restrict__ kvb =
      (const char*)kvp + (size_t)(b * N * NH + g) * 128;
  const int lane16 = e8 * 16;

  const int chn = g * CH + e8 * 4;
  const float4 q0 = *(const float4*)(qp + (size_t)(b * N + n) * C + chn);
  const __half2 q01 = __floats2half2_rn(q0.x * LOG2E, q0.y * LOG2E);
  const __half2 q23 = __floats2half2_rn(q0.z * LOG2E, q0.w * LOG2E);
  const h16x2 one2 = {(_Float16)1.0f, (_Float16)1.0f};

  float ev7[KW];  // attn weights of the row this lane owns (lane e8 -> row e8)
#pragma unroll
  for (int i = 0; i < KW; ++i) ev7[i] = 0.f;
  float4 acc = {0.f, 0.f, 0.f, 0.f};  // unnormalized e-weighted V sum
  float d0 = 0.f, d1 = 0.f;           // two denom chains

  // row base (bytes, row stride 64KB) incl. per-lane channel chunk
#define ROWBASE(iy) ((min(max(cy + (iy)-R, 0), H - 1) << 16) + lane16)
#define LOADROW(buf, iy)                                      \
  {                                                           \
    const int _rb = ROWBASE(iy);                              \
    _Pragma("unroll") for (int ix = 0; ix < KW; ++ix)         \
        buf[ix].f = *(const float4*)(kvb + (_rb + pxo[ix]));  \
  }
#define COMPROW(buf, iy)                                                     \
  {                                                                          \
    const bool _own = ((iy) == e8);                                          \
    _Pragma("unroll") for (int ix = 0; ix < KW; ++ix) {                      \
      const h16x2 d01 = h2n(__habs2(__hsub2(q01, buf[ix].h[0])));            \
      const h16x2 d23 = h2n(__habs2(__hsub2(q23, buf[ix].h[1])));            \
      float s = __builtin_amdgcn_fdot2(                                      \
          d01, one2, __builtin_amdgcn_fdot2(d23, one2, 0.0f, false), false); \
      s += dpp_mov<DPP_QUAD_XOR1>(s);                                        \
      s += dpp_mov<DPP_QUAD_XOR2>(s);                                        \
      s += dpp_mov<DPP_HALF_MIRROR>(s);                                      \
      const float e = __builtin_amdgcn_exp2f(-s); /* sim<=0: no max shift */ \
      if (ix & 1) d1 += e; else d0 += e;                                     \
      if (_own) ev7[ix] = e;                                                 \
      const h16x2 v01 = buf[ix].n[2], v23 = buf[ix].n[3];                    \
      acc.x = fmaf(e, (float)v01.x, acc.x);                                  \
      acc.y = fmaf(e, (float)v01.y, acc.y);                                  \
      acc.z = fmaf(e, (float)v23.x, acc.z);                                  \
      acc.w = fmaf(e, (float)v23.y, acc.w);                                  \
    }                                                                        \
  }

  // Depth-2 pipeline: period-3 rotation A/B/C. During every COMPROW, the
  // next TWO rows (>=14 loads) are structurally in flight, and the loads
  // issued late in the body cross the runtime backedge (R8: cannot be sunk).
  KV A[KW], Bf[KW], Cf[KW];
  LOADROW(A, 0)
  LOADROW(Bf, 1)
#pragma clang loop unroll(disable)
  for (int ty = 0; ty < KW - 3; ty += 3) {  // ty = 0, 3
    LOADROW(Cf, ty + 2)
    COMPROW(A, ty)
    LOADROW(A, ty + 3)
    COMPROW(Bf, ty + 1)
    if (ty + 4 < KW) LOADROW(Bf, ty + 4)
    COMPROW(Cf, ty + 2)
  }
  COMPROW(A, KW - 1)  // epilogue: row 6 (loaded in last iteration)

  const float inv = 1.0f / (d0 + d1);
  float4 o;
  o.x = acc.x * inv; o.y = acc.y * inv; o.z = acc.z * inv; o.w = acc.w * inv;
  *(float4*)(outp + (size_t)(b * N + n) * C + chn) = o;

  // lane e8 (<7) writes window row e8 of attn, normalized, exactly once
  if (e8 < KW) {
    float* attn_row = attnp + ((size_t)(b * N + n) * NH + g) * KK + e8 * KW;
#pragma unroll
    for (int ix = 0; ix < KW; ++ix) attn_row[ix] = ev7[ix] * inv;
  }
}

extern "C" void kernel_launch(void* const* d_in, const int* in_sizes, int n_in,
                              void* d_out, int out_size, void* d_ws, size_t ws_size,
                              hipStream_t stream) {
  const float* moff = (const float*)d_in[0];  // [B,N,h,2]
  const float* q    = (const float*)d_in[1];  // [B,N,C]
  const float* k    = (const float*)d_in[2];  // [B,N,C]
  const float* v    = (const float*)d_in[3];  // [B,N,C]
  float* out  = (float*)d_out;            // [B,N,C]
  float* attn = out + (size_t)B * N * C;  // [B,N,h,K]
  __half* kv = (__half*)d_ws;             // packed fp16 kv, 8.4 MB

  pack_kv_kernel<<<B * N * NH * 8 / 256, 256, 0, stream>>>(k, v, kv);
  const int grid = B * NH * N / PIX;  // 2048 blocks of 256 threads
  match_attn_kernel<<<grid, 256, 0, stream>>>(moff, q, kv, out, attn);
}

// Round 2
// 109.375 us; speedup vs baseline: 1.5928x; 1.5928x over previous
//
#include <hip/hip_runtime.h>
#include <hip/hip_fp16.h>
#include <math.h>

// MatchAttention fused forward — v3 (R0 pipeline structure + VALU diet).
// B=2, H=W=64 (N=4096), C=256, h=8 (Ch=32), 7x7=49 window.
//
// Ledger: load batches survive ONLY when they cross a runtime-loop
// backedge with no intervening control flow (R8: VGPR 88 kept batches;
// R9/R10 full unroll collapsed them; R1-v2 period-3 rotation +
// launch_bounds(256,4) + conditional LOADROW collapsed them again ->
// VGPR 64, 93us). v3 = exact R0 structure (period-2 A/B, ty+=2 backedge,
// launch_bounds(256,2), unconditional loads) with the R1 VALU diet kept:
// v_dot2_f32_f16 L1-reduce, exp2-prescale (k,q pre-multiplied by log2e
// -> v_exp_f32 direct), fp16-source fmaf V-accumulate, saddr-form
// gathers (wave-uniform 64b base in SGPR, per-lane 32b voffset).
constexpr int B = 2, H = 64, W = 64, C = 256, NH = 8, CH = 32;
constexpr int R = 3, KW = 7, KK = 49, N = H * W;
constexpr int PIX = 32;  // pixel-heads per 256-thread block (8 lanes each)
constexpr float LOG2E = 1.4426950408889634f;

typedef _Float16 h16x2 __attribute__((ext_vector_type(2)));

template <int CTRL>
static __device__ __forceinline__ float dpp_mov(float v) {
  union { float f; int i; } u;
  u.f = v;
  u.i = __builtin_amdgcn_update_dpp(u.i, u.i, CTRL, 0xf, 0xf, true);
  return u.f;
}
#define DPP_QUAD_XOR1 0xB1     // quad_perm [1,0,3,2]
#define DPP_QUAD_XOR2 0x4E     // quad_perm [2,3,0,1]
#define DPP_HALF_MIRROR 0x141  // lane i -> 7-i within each 8-lane group

static __device__ __forceinline__ h16x2 h2n(__half2 x) {
  union { __half2 h; h16x2 n; } u;
  u.h = x;
  return u.n;
}

// pack k,v fp32 -> fp16 interleaved: [b][n][g][(k0..3 v0..3) x 8] = 128B.
// k is pre-scaled by log2(e): exp2(-log2e*sum|q-k|) == exp(-sum|q-k|),
// so the match kernel feeds the raw L1 sum straight into v_exp_f32.
// v stays unscaled.
__global__ void __launch_bounds__(256) pack_kv_kernel(
    const float* __restrict__ kp, const float* __restrict__ vp,
    __half* __restrict__ kv) {
  const int idx = blockIdx.x * 256 + threadIdx.x;  // 0..524287
  const int e8 = idx & 7;
  const int g = (idx >> 3) & 7;
  const int bn = idx >> 6;  // 0..8191 = b*N+n
  const float4 kf = *(const float4*)(kp + (size_t)bn * C + g * CH + e8 * 4);
  const float4 vf = *(const float4*)(vp + (size_t)bn * C + g * CH + e8 * 4);
  __half2 o[4];
  o[0] = __floats2half2_rn(kf.x * LOG2E, kf.y * LOG2E);
  o[1] = __floats2half2_rn(kf.z * LOG2E, kf.w * LOG2E);
  o[2] = __floats2half2_rn(vf.x, vf.y);
  o[3] = __floats2half2_rn(vf.z, vf.w);
  *(float4*)(kv + ((size_t)(bn * NH + g) * 64 + e8 * 8)) = *(float4*)o;
}

union KV { float4 f; __half2 h[4]; h16x2 n[4]; };

__global__ void __launch_bounds__(256, 2) match_attn_kernel(
    const float* __restrict__ moff, const float* __restrict__ qp,
    const __half* __restrict__ kvp, float* __restrict__ outp,
    float* __restrict__ attnp) {
  const int t = threadIdx.x;
  const int e8 = t & 7;  // which 4-channel slice of the head
  const int p = t >> 3;  // pixel within block, 0..31

  // XCD swizzle: blk&7 ~ XCD; XCD x owns (b,g) pairs {2x,2x+1}
  const int xcd = blockIdx.x & 7;
  const int rest = blockIdx.x >> 3;      // 0..255
  const int bg = xcd * 2 + (rest >> 7);  // 0..15
  const int slot = rest & 127;
  const int y = slot >> 1;
  const int x = (slot & 1) * PIX + p;
  const int g = bg & 7;
  const int b = bg >> 3;
  const int n = y * W + x;

  // per-pixel, per-head rounded (dy,dx); rintf == jnp.round (half-to-even)
  const float2 off = *(const float2*)(moff + ((size_t)(b * N + n) * NH + g) * 2);
  const int cy = y + (int)rintf(off.x);
  const int cx = x + (int)rintf(off.y);

  // clamped x offsets in BYTES (pixel stride 1024B)
  int pxo[KW];
#pragma unroll
  for (int i = 0; i < KW; ++i) pxo[i] = min(max(cx + i - R, 0), W - 1) << 10;
  // wave-uniform image base (b,g are blockIdx-derived -> SGPR pair);
  // per-lane terms live in the 32-bit voffset -> saddr-form loads.
  const char* __restrict__ kvb =
      (const char*)kvp + (size_t)(b * N * NH + g) * 128;
  const int lane16 = e8 * 16;

  const int chn = g * CH + e8 * 4;
  const float4 q0 = *(const float4*)(qp + (size_t)(b * N + n) * C + chn);
  const __half2 q01 = __floats2half2_rn(q0.x * LOG2E, q0.y * LOG2E);
  const __half2 q23 = __floats2half2_rn(q0.z * LOG2E, q0.w * LOG2E);
  const h16x2 one2 = {(_Float16)1.0f, (_Float16)1.0f};

  float ev7[KW];  // attn weights of the row this lane owns (lane e8 -> row e8)
#pragma unroll
  for (int i = 0; i < KW; ++i) ev7[i] = 0.f;
  float4 acc = {0.f, 0.f, 0.f, 0.f};  // unnormalized e-weighted V sum
  float d0 = 0.f, d1 = 0.f;           // two denom chains

  // row base (bytes, row stride 64KB) incl. per-lane channel chunk
#define ROWBASE(iy) ((min(max(cy + (iy)-R, 0), H - 1) << 16) + lane16)
#define LOADROW(buf, iy)                                      \
  {                                                           \
    const int _rb = ROWBASE(iy);                              \
    _Pragma("unroll") for (int ix = 0; ix < KW; ++ix)         \
        buf[ix].f = *(const float4*)(kvb + (_rb + pxo[ix]));  \
  }
#define COMPROW(buf, iy)                                                     \
  {                                                                          \
    const bool _own = ((iy) == e8);                                          \
    _Pragma("unroll") for (int ix = 0; ix < KW; ++ix) {                      \
      const h16x2 d01 = h2n(__habs2(__hsub2(q01, buf[ix].h[0])));            \
      const h16x2 d23 = h2n(__habs2(__hsub2(q23, buf[ix].h[1])));            \
      float s = __builtin_amdgcn_fdot2(                                      \
          d01, one2, __builtin_amdgcn_fdot2(d23, one2, 0.0f, false), false); \
      s += dpp_mov<DPP_QUAD_XOR1>(s);                                        \
      s += dpp_mov<DPP_QUAD_XOR2>(s);                                        \
      s += dpp_mov<DPP_HALF_MIRROR>(s);                                      \
      const float e = __builtin_amdgcn_exp2f(-s); /* sim<=0: no max shift */ \
      if (ix & 1) d1 += e; else d0 += e;                                     \
      if (_own) ev7[ix] = e;                                                 \
      const h16x2 v01 = buf[ix].n[2], v23 = buf[ix].n[3];                    \
      acc.x = fmaf(e, (float)v01.x, acc.x);                                  \
      acc.y = fmaf(e, (float)v01.y, acc.y);                                  \
      acc.z = fmaf(e, (float)v23.x, acc.z);                                  \
      acc.w = fmaf(e, (float)v23.y, acc.w);                                  \
    }                                                                        \
  }

  KV A[KW], Bf[KW];
  LOADROW(A, 0)  // prologue: row 0 in flight
#pragma clang loop unroll(disable)
  for (int ty = 0; ty < KW - 1; ty += 2) {  // ty = 0,2,4 — runtime backedge
    LOADROW(Bf, ty + 1)   // issue row ty+1 while row ty computes
    COMPROW(A, ty)
    LOADROW(A, ty + 2)    // issue row ty+2; crosses the backedge -> cannot
    COMPROW(Bf, ty + 1)   //   be sunk by the scheduler (R8 evidence)
  }
  COMPROW(A, KW - 1)      // epilogue: row 6

  const float inv = 1.0f / (d0 + d1);
  float4 o;
  o.x = acc.x * inv; o.y = acc.y * inv; o.z = acc.z * inv; o.w = acc.w * inv;
  *(float4*)(outp + (size_t)(b * N + n) * C + chn) = o;

  // lane e8 (<7) writes window row e8 of attn, normalized, exactly once
  if (e8 < KW) {
    float* attn_row = attnp + ((size_t)(b * N + n) * NH + g) * KK + e8 * KW;
#pragma unroll
    for (int ix = 0; ix < KW; ++ix) attn_row[ix] = ev7[ix] * inv;
  }
}

extern "C" void kernel_launch(void* const* d_in, const int* in_sizes, int n_in,
                              void* d_out, int out_size, void* d_ws, size_t ws_size,
                              hipStream_t stream) {
  const float* moff = (const float*)d_in[0];  // [B,N,h,2]
  const float* q    = (const float*)d_in[1];  // [B,N,C]
  const float* k    = (const float*)d_in[2];  // [B,N,C]
  const float* v    = (const float*)d_in[3];  // [B,N,C]
  float* out  = (float*)d_out;            // [B,N,C]
  float* attn = out + (size_t)B * N * C;  // [B,N,h,K]
  __half* kv = (__half*)d_ws;             // packed fp16 kv, 8.4 MB

  pack_kv_kernel<<<B * N * NH * 8 / 256, 256, 0, stream>>>(k, v, kv);
  const int grid = B * NH * N / PIX;  // 2048 blocks of 256 threads
  match_attn_kernel<<<grid, 256, 0, stream>>>(moff, q, kv, out, attn);
}